// Round 1
// baseline (1070.813 us; speedup 1.0000x reference)
//
#include <hip/hip_runtime.h>

typedef float f2 __attribute__((ext_vector_type(2)));

__device__ __forceinline__ f2 fma2(f2 a, f2 b, f2 c) { return __builtin_elementwise_fma(a, b, c); }
__device__ __forceinline__ float sigm(float x) { float e = __expf(-x); return __builtin_amdgcn_rcpf(1.f + e); }

#define B_ 64
#define L_ 512
#define T_ 50
#define H_ 100

// ---------------- BiLSTM kernel: one block per (batch, direction) ----------------
// 256 threads, 200 active. Thread 2k   -> rows (i_k, g_k)
//                          Thread 2k+1 -> rows (f_k, o_k), owns c_k.
// Weights register-resident (304 VGPR). h broadcast via LDS ping-pong, 1 barrier/step.
// Token rows staged in 16-step LDS chunks, double-buffered, prefetched into regs.
__global__ __launch_bounds__(256, 1) void lstm_kernel(
    const int* __restrict__ ids, const float* __restrict__ tokt,
    const float* __restrict__ wihf, const float* __restrict__ whhf,
    const float* __restrict__ bihf, const float* __restrict__ bhhf,
    const float* __restrict__ wihb, const float* __restrict__ whhb,
    const float* __restrict__ bihb, const float* __restrict__ bhhb,
    float* __restrict__ out)
{
    __shared__ __align__(16) float xbuf[2][16][64];
    __shared__ __align__(16) float hbuf[2][100];

    const int blk = blockIdx.x;
    const int b = blk >> 1, dir = blk & 1;
    const int tid = threadIdx.x;

    const float* wih = dir ? wihb : wihf;
    const float* whh = dir ? whhb : whhf;
    const float* bih = dir ? bihb : bihf;
    const float* bhh = dir ? bhhb : bhhf;

    const int k_raw = tid >> 1, r = tid & 1;
    const int k = (k_raw < 100) ? k_raw : 99;          // clamp for idle lanes
    const bool wr = (tid < 200) && (r == 1);
    const int rowA = (r ? 100 : 0) + k;                // i or f
    const int rowB = (r ? 300 : 200) + k;              // o or g

    f2 wiA[26], wiB[26], whA[50], whB[50];
#pragma unroll
    for (int j = 0; j < 25; ++j) {
        wiA[j] = *(const f2*)&wih[rowA * T_ + 2 * j];
        wiB[j] = *(const f2*)&wih[rowB * T_ + 2 * j];
    }
    wiA[25] = f2{0.f, 0.f}; wiB[25] = f2{0.f, 0.f};
#pragma unroll
    for (int j = 0; j < 50; ++j) {
        whA[j] = *(const f2*)&whh[rowA * H_ + 2 * j];
        whB[j] = *(const f2*)&whh[rowB * H_ + 2 * j];
    }
    const float biasA = bih[rowA] + bhh[rowA];
    const float biasB = bih[rowB] + bhh[rowB];

    const int ids_base = b * L_;
    float pre[4];

    // issue + commit chunk 0
#pragma unroll
    for (int i = 0; i < 4; ++i) {
        int e = tid + i * 256; int sl = e >> 6, j = e & 63;
        int l = dir ? (L_ - 1 - sl) : sl;
        int id = ids[ids_base + l];
        int jj = (j < T_) ? j : 0;
        float v = tokt[id * T_ + jj];
        pre[i] = (j < T_) ? v : 0.f;
    }
#pragma unroll
    for (int i = 0; i < 4; ++i) { int e = tid + i * 256; xbuf[0][e >> 6][e & 63] = pre[i]; }
    // issue chunk 1
#pragma unroll
    for (int i = 0; i < 4; ++i) {
        int e = tid + i * 256; int sl = e >> 6, j = e & 63;
        int s = 16 + sl;
        int l = dir ? (L_ - 1 - s) : s;
        int id = ids[ids_base + l];
        int jj = (j < T_) ? j : 0;
        float v = tokt[id * T_ + jj];
        pre[i] = (j < T_) ? v : 0.f;
    }
    if (tid < 100) hbuf[0][tid] = 0.f;
    __syncthreads();

    float c = 0.f;
    for (int s = 0; s < L_; ++s) {
        const int cb = (s >> 4) & 1, sl = s & 15, par = s & 1;
        const float* xrow = &xbuf[cb][sl][0];
        const float* hrow = &hbuf[par][0];

        f2 aA = f2{0.f, 0.f}, aB = f2{0.f, 0.f};
#pragma unroll
        for (int j = 0; j < 25; ++j) {
            float4 hv = *(const float4*)&hrow[4 * j];
            f2 h01 = f2{hv.x, hv.y}, h23 = f2{hv.z, hv.w};
            aA = fma2(whA[2 * j],     h01, aA);
            aA = fma2(whA[2 * j + 1], h23, aA);
            aB = fma2(whB[2 * j],     h01, aB);
            aB = fma2(whB[2 * j + 1], h23, aB);
        }
#pragma unroll
        for (int j = 0; j < 13; ++j) {
            float4 xv = *(const float4*)&xrow[4 * j];
            f2 x01 = f2{xv.x, xv.y}, x23 = f2{xv.z, xv.w};
            aA = fma2(wiA[2 * j],     x01, aA);
            aB = fma2(wiB[2 * j],     x01, aB);
            aA = fma2(wiA[2 * j + 1], x23, aA);
            aB = fma2(wiB[2 * j + 1], x23, aB);
        }
        float pA = biasA + aA.x + aA.y;   // i (r=0) or f (r=1)
        float pB = biasB + aB.x + aB.y;   // g (r=0) or o (r=1)

        float sA = sigm(pA);
        float inB = r ? pB : 2.f * pB;
        float sB = sigm(inB);
        float gB = r ? sB : 2.f * sB - 1.f;      // r=0: tanh(g), r=1: sigmoid(o)

        float t0 = r ? sA * c : sA * gB;         // r=1: f*c_old ; r=0: i*g
        float t1 = __shfl_xor(t0, 1, 64);
        float cn = t0 + t1;
        c = cn;                                  // both lanes track c identically

        float th = 2.f * sigm(2.f * cn) - 1.f;   // tanh(c_new)
        float hv_ = gB * th;                     // valid on r=1: o * tanh(c)

        if (wr) {
            hbuf[par ^ 1][k] = hv_;
            int l = dir ? (L_ - 1 - s) : s;
            out[(b * L_ + l) * 204 + (dir ? 104 : 0) + k] = hv_;
        }

        if (sl == 15) {
            int nc = (s >> 4) + 1;
            if (nc < 32) {
#pragma unroll
                for (int i = 0; i < 4; ++i) { int e = tid + i * 256; xbuf[nc & 1][e >> 6][e & 63] = pre[i]; }
                if (nc + 1 < 32) {
#pragma unroll
                    for (int i = 0; i < 4; ++i) {
                        int e = tid + i * 256; int sl2 = e >> 6, j = e & 63;
                        int s2 = (nc + 1) * 16 + sl2;
                        int l2 = dir ? (L_ - 1 - s2) : s2;
                        int id = ids[ids_base + l2];
                        int jj = (j < T_) ? j : 0;
                        float v = tokt[id * T_ + jj];
                        pre[i] = (j < T_) ? v : 0.f;
                    }
                }
            }
        }
        __syncthreads();
    }
}

// ---------------- Attention kernel: one block per (batch, 32-l chunk) ----------------
// score = cat . (W_proj^T hidden) + b_proj . hidden   (factorized; 4x less work)
__global__ __launch_bounds__(256, 1) void attn_kernel(
    const float* __restrict__ lex, const int* __restrict__ pids,
    const int* __restrict__ bmes, const int* __restrict__ lmask,
    const float* __restrict__ pint, const float* __restrict__ wp,
    const float* __restrict__ bp, float* __restrict__ out)
{
    __shared__ __align__(16) float wpT[105 * 104];   // [f(104)+bp][h], 43.7 KB
    __shared__ __align__(16) float vv[32 * 108];     // per-pair projected vec + s0
    __shared__ __align__(16) float hid[32 * 100];
    __shared__ __align__(16) float catl[32 * 4 * 104];
    __shared__ float wts[32 * 4];

    const int b = blockIdx.x >> 4, ch = blockIdx.x & 15;
    const int l0 = ch * 32;
    const int tid = threadIdx.x;
    const int bl0 = b * L_ + l0;

    // stage w_proj^T (+ b_proj as row 104) — coalesced global reads
    for (int e = tid; e < 10500; e += 256) {
        if (e < 10400) { int h = e / 104, f = e % 104; wpT[f * 104 + h] = wp[e]; }
        else           { int h = e - 10400; wpT[104 * 104 + h] = bp[h]; }
    }
    // hidden = h_f + h_b (h_b stashed at [104:204]); also finalize out[...,0:100]
    for (int e = tid; e < 3200; e += 256) {
        int p = e / 100, q = e % 100; int bl = bl0 + p;
        float s = out[bl * 204 + q] + out[bl * 204 + 104 + q];
        hid[p * 100 + q] = s; out[bl * 204 + q] = s;
    }
    // cat = [onehot(bmes,4) | lex(50) | pinyin_emb(50)]
    for (int e = tid; e < 13312; e += 256) {
        int p = e / 416, rem = e % 416; int w = rem / 104, f = rem % 104;
        int blw = (bl0 + p) * 4 + w; float v;
        if (f < 4)       v = (bmes[blw] == f) ? 1.f : 0.f;
        else if (f < 54) v = lex[blw * 50 + (f - 4)];
        else             v = pint[pids[blw] * 50 + (f - 54)];
        catl[e] = v;
    }
    __syncthreads();

    // v[p][f] = sum_h hid[p][h] * wpT[f][h];  f==104 row gives s0 = bp . hid
    {
        const int grp = tid >> 7; const int f = tid & 127; const int p0 = grp * 16;
        f2 acc[16];
#pragma unroll
        for (int i = 0; i < 16; ++i) acc[i] = f2{0.f, 0.f};
        const float* wrow = &wpT[((f < 105) ? f : 104) * 104];
        for (int hh = 0; hh < 25; ++hh) {
            float4 wv = *(const float4*)&wrow[4 * hh];
            f2 w01 = f2{wv.x, wv.y}, w23 = f2{wv.z, wv.w};
#pragma unroll
            for (int pp = 0; pp < 16; ++pp) {
                float4 hv = *(const float4*)&hid[(p0 + pp) * 100 + 4 * hh];  // broadcast
                acc[pp] = fma2(w01, f2{hv.x, hv.y}, acc[pp]);
                acc[pp] = fma2(w23, f2{hv.z, hv.w}, acc[pp]);
            }
        }
        if (f < 105) {
#pragma unroll
            for (int pp = 0; pp < 16; ++pp) vv[(p0 + pp) * 108 + f] = acc[pp].x + acc[pp].y;
        }
    }
    __syncthreads();

    // scores + masked softmax over W=4 (quad shuffles)
    if (tid < 128) {
        int p = tid >> 2, w = tid & 3;
        const float* vrow = &vv[p * 108];
        const float* crow = &catl[p * 416 + w * 104];
        f2 a = f2{0.f, 0.f};
#pragma unroll
        for (int ff = 0; ff < 26; ++ff) {
            float4 cv = *(const float4*)&crow[4 * ff];
            float4 v4 = *(const float4*)&vrow[4 * ff];
            a = fma2(f2{cv.x, cv.y}, f2{v4.x, v4.y}, a);
            a = fma2(f2{cv.z, cv.w}, f2{v4.z, v4.w}, a);
        }
        float sc = a.x + a.y + vrow[104];
        if (lmask[(bl0 + p) * 4 + w] == 0) sc = -1e9f;
        float m = fmaxf(sc, __shfl_xor(sc, 1, 64)); m = fmaxf(m, __shfl_xor(m, 2, 64));
        float e = __expf(sc - m);
        float ss = e + __shfl_xor(e, 1, 64); ss += __shfl_xor(ss, 2, 64);
        wts[p * 4 + w] = e * __builtin_amdgcn_rcpf(ss);
    }
    __syncthreads();

    // att[p][f] = sum_w wts * cat  -> out[...,100:204]
    for (int e = tid; e < 3328; e += 256) {
        int p = e / 104, f = e % 104;
        const float* cp = &catl[p * 416 + f];
        float a = wts[p * 4] * cp[0] + wts[p * 4 + 1] * cp[104]
                + wts[p * 4 + 2] * cp[208] + wts[p * 4 + 3] * cp[312];
        out[(bl0 + p) * 204 + 100 + f] = a;
    }
}

extern "C" void kernel_launch(void* const* d_in, const int* in_sizes, int n_in,
                              void* d_out, int out_size, void* d_ws, size_t ws_size,
                              hipStream_t stream) {
    const int*   ids   = (const int*)d_in[0];
    const float* lex   = (const float*)d_in[1];
    const int*   pids  = (const int*)d_in[2];
    const int*   bmes  = (const int*)d_in[3];
    const int*   lmask = (const int*)d_in[4];
    // d_in[5] att_token_mask: all ones -> unused (packed BiLSTM == full-length)
    const float* tokt  = (const float*)d_in[6];
    const float* pint  = (const float*)d_in[7];
    const float* wihf  = (const float*)d_in[8];
    const float* whhf  = (const float*)d_in[9];
    const float* bihf  = (const float*)d_in[10];
    const float* bhhf  = (const float*)d_in[11];
    const float* wihb  = (const float*)d_in[12];
    const float* whhb  = (const float*)d_in[13];
    const float* bihb  = (const float*)d_in[14];
    const float* bhhb  = (const float*)d_in[15];
    const float* wp    = (const float*)d_in[16];
    const float* bp    = (const float*)d_in[17];
    float* out = (float*)d_out;

    lstm_kernel<<<128, 256, 0, stream>>>(ids, tokt, wihf, whhf, bihf, bhhf,
                                         wihb, whhb, bihb, bhhb, out);
    attn_kernel<<<1024, 256, 0, stream>>>(lex, pids, bmes, lmask, pint, wp, bp, out);
}

// Round 2
// 620.840 us; speedup vs baseline: 1.7248x; 1.7248x over previous
//
#include <hip/hip_runtime.h>

typedef float f2 __attribute__((ext_vector_type(2)));

__device__ __forceinline__ f2 fma2(f2 a, f2 b, f2 c) { return __builtin_elementwise_fma(a, b, c); }
__device__ __forceinline__ float sigm(float x) { float e = __expf(-x); return __builtin_amdgcn_rcpf(1.f + e); }
__device__ __forceinline__ float dpp_xor1(float x) {
    return __int_as_float(__builtin_amdgcn_mov_dpp(__float_as_int(x), 0xB1, 0xF, 0xF, true));
}

#define B_ 64
#define L_ 512
#define T_ 50
#define H_ 100
#define XGN (B_ * L_ * 400)   // floats per direction of xg scratch

// ---------------- xg GEMM: gate pre-activations from inputs, all steps ----------------
// xg[dir][b][step][400] (dir=1 stored in step order, i.e. reversed l).
// x-row is wave-uniform -> scalar loads feed v_fmac(s,v): no LDS, no broadcasts.
__global__ __launch_bounds__(256, 2) void xg_gemm(
    const int* __restrict__ ids, const float* __restrict__ tokt,
    const float* __restrict__ wihf, const float* __restrict__ wihb,
    float* __restrict__ xg)
{
    const int blk = blockIdx.x, dir = blk >> 10, rest = blk & 1023;
    const int b = rest >> 4, lc = rest & 15, l0 = lc * 32;
    const int tid = threadIdx.x, k_raw = tid >> 1, r = tid & 1;
    const int k = (k_raw < 100) ? k_raw : 99;
    const bool act = tid < 200;
    const int rowA = r * 100 + k, rowB = 200 + r * 100 + k;
    const float* wih = dir ? wihb : wihf;

    float wA[50], wB[50];
#pragma unroll
    for (int j = 0; j < 50; ++j) { wA[j] = wih[rowA * T_ + j]; wB[j] = wih[rowB * T_ + j]; }

    float* xgd = xg + (size_t)dir * XGN;
    for (int p = 0; p < 32; ++p) {
        int l = l0 + p;
        int id = ids[b * L_ + l];                    // uniform -> s_load
        const float* xr = tokt + (size_t)id * T_;    // uniform row
        float aA0 = 0.f, aA1 = 0.f, aB0 = 0.f, aB1 = 0.f;
#pragma unroll
        for (int j = 0; j < 50; j += 2) {
            float x0 = xr[j], x1 = xr[j + 1];        // uniform -> scalar loads
            aA0 = fmaf(x0, wA[j], aA0); aA1 = fmaf(x1, wA[j + 1], aA1);
            aB0 = fmaf(x0, wB[j], aB0); aB1 = fmaf(x1, wB[j + 1], aB1);
        }
        int idx = dir ? (L_ - 1 - l) : l;            // step-ordered store
        float* o = xgd + ((size_t)b * L_ + idx) * 400;
        if (act) { o[rowA] = aA0 + aA1; o[rowB] = aB0 + aB1; }
    }
}

// ---------------- BiLSTM recurrence: one block per (batch, direction) ----------------
// Per-thread weights = W_hh rows only (200 VGPR). xg chunks double-buffered in LDS.
__global__ __launch_bounds__(256, 1) void lstm2(
    const float* __restrict__ xg,
    const float* __restrict__ whhf, const float* __restrict__ bihf, const float* __restrict__ bhhf,
    const float* __restrict__ whhb, const float* __restrict__ bihb, const float* __restrict__ bhhb,
    float* __restrict__ out)
{
    __shared__ __align__(16) float xgbuf[2][16 * 400];
    __shared__ __align__(16) float hbuf[2][100];

    const int blk = blockIdx.x, b = blk >> 1, dir = blk & 1, tid = threadIdx.x;
    const float* whh = dir ? whhb : whhf;
    const float* bih = dir ? bihb : bihf;
    const float* bhh = dir ? bhhb : bhhf;
    const float* xgd = xg + (size_t)dir * XGN + (size_t)b * L_ * 400;

    const int k_raw = tid >> 1, r = tid & 1;
    const int k = (k_raw < 100) ? k_raw : 99;
    const bool wr = (tid < 200) && (r == 1);
    const int rowA = r * 100 + k, rowB = 200 + r * 100 + k;

    f2 whA[50], whB[50];
#pragma unroll
    for (int j = 0; j < 50; ++j) {
        whA[j] = *(const f2*)&whh[rowA * H_ + 2 * j];
        whB[j] = *(const f2*)&whh[rowB * H_ + 2 * j];
    }
    const float biasA = bih[rowA] + bhh[rowA];
    const float biasB = bih[rowB] + bhh[rowB];

    // stage chunk 0
    {
        const float4* s4 = (const float4*)xgd;
        float4* d4 = (float4*)xgbuf[0];
#pragma unroll
        for (int t = 0; t < 7; ++t) { int e = tid + 256 * t; if (e < 1600) d4[e] = s4[e]; }
    }
    if (tid < 100) hbuf[0][tid] = 0.f;
    __syncthreads();

    float c = 0.f;
    for (int s = 0; s < L_; ++s) {
        const int m = s >> 4, sl = s & 15, par = s & 1;
        if (sl == 0 && m + 1 < 32) {   // stage next chunk (buffer freed by last barrier)
            const float4* s4 = (const float4*)(xgd + (size_t)(m + 1) * 16 * 400);
            float4* d4 = (float4*)xgbuf[(m + 1) & 1];
#pragma unroll
            for (int t = 0; t < 7; ++t) { int e = tid + 256 * t; if (e < 1600) d4[e] = s4[e]; }
        }
        const float* hrow = hbuf[par];
        const float* xrow = &xgbuf[m & 1][sl * 400];

        f2 a0{0.f,0.f}, a1{0.f,0.f}, b0{0.f,0.f}, b1{0.f,0.f};
#pragma unroll
        for (int j = 0; j < 25; ++j) {
            float4 hv = ((const float4*)hrow)[j];
            a0 = fma2(whA[2 * j],     f2{hv.x, hv.y}, a0);
            a1 = fma2(whA[2 * j + 1], f2{hv.z, hv.w}, a1);
            b0 = fma2(whB[2 * j],     f2{hv.x, hv.y}, b0);
            b1 = fma2(whB[2 * j + 1], f2{hv.z, hv.w}, b1);
        }
        float pA = biasA + xrow[rowA] + a0.x + a0.y + a1.x + a1.y;  // i (r=0) / f (r=1)
        float pB = biasB + xrow[rowB] + b0.x + b0.y + b1.x + b1.y;  // g (r=0) / o (r=1)

        float sA = sigm(pA);
        float inB = r ? pB : 2.f * pB;
        float sB = sigm(inB);
        float gB = r ? sB : 2.f * sB - 1.f;     // r=0: tanh(g), r=1: sigmoid(o)

        float t0 = r ? sA * c : sA * gB;        // f*c_old / i*g
        float t1 = dpp_xor1(t0);                // pairwise exchange on VALU pipe
        float cn = t0 + t1; c = cn;

        float th = 2.f * sigm(2.f * cn) - 1.f;  // tanh(c)
        float hv_ = gB * th;

        if (wr) {
            hbuf[par ^ 1][k] = hv_;
            int l = dir ? (L_ - 1 - s) : s;
            out[((size_t)b * L_ + l) * 204 + (dir ? 104 : 0) + k] = hv_;
        }
        __syncthreads();
    }
}

// ---------------- Fallback BiLSTM (round-1, used when ws too small) ----------------
__global__ __launch_bounds__(256, 1) void lstm_fb(
    const int* __restrict__ ids, const float* __restrict__ tokt,
    const float* __restrict__ wihf, const float* __restrict__ whhf,
    const float* __restrict__ bihf, const float* __restrict__ bhhf,
    const float* __restrict__ wihb, const float* __restrict__ whhb,
    const float* __restrict__ bihb, const float* __restrict__ bhhb,
    float* __restrict__ out)
{
    __shared__ __align__(16) float xbuf[2][16][64];
    __shared__ __align__(16) float hbuf[2][100];
    const int blk = blockIdx.x;
    const int b = blk >> 1, dir = blk & 1;
    const int tid = threadIdx.x;
    const float* wih = dir ? wihb : wihf;
    const float* whh = dir ? whhb : whhf;
    const float* bih = dir ? bihb : bihf;
    const float* bhh = dir ? bhhb : bhhf;
    const int k_raw = tid >> 1, r = tid & 1;
    const int k = (k_raw < 100) ? k_raw : 99;
    const bool wr = (tid < 200) && (r == 1);
    const int rowA = (r ? 100 : 0) + k;
    const int rowB = (r ? 300 : 200) + k;
    f2 wiA[26], wiB[26], whA[50], whB[50];
#pragma unroll
    for (int j = 0; j < 25; ++j) {
        wiA[j] = *(const f2*)&wih[rowA * T_ + 2 * j];
        wiB[j] = *(const f2*)&wih[rowB * T_ + 2 * j];
    }
    wiA[25] = f2{0.f, 0.f}; wiB[25] = f2{0.f, 0.f};
#pragma unroll
    for (int j = 0; j < 50; ++j) {
        whA[j] = *(const f2*)&whh[rowA * H_ + 2 * j];
        whB[j] = *(const f2*)&whh[rowB * H_ + 2 * j];
    }
    const float biasA = bih[rowA] + bhh[rowA];
    const float biasB = bih[rowB] + bhh[rowB];
    const int ids_base = b * L_;
    float pre[4];
#pragma unroll
    for (int i = 0; i < 4; ++i) {
        int e = tid + i * 256; int sl = e >> 6, j = e & 63;
        int l = dir ? (L_ - 1 - sl) : sl;
        int id = ids[ids_base + l];
        int jj = (j < T_) ? j : 0;
        float v = tokt[id * T_ + jj];
        pre[i] = (j < T_) ? v : 0.f;
    }
#pragma unroll
    for (int i = 0; i < 4; ++i) { int e = tid + i * 256; xbuf[0][e >> 6][e & 63] = pre[i]; }
#pragma unroll
    for (int i = 0; i < 4; ++i) {
        int e = tid + i * 256; int sl = e >> 6, j = e & 63;
        int s = 16 + sl;
        int l = dir ? (L_ - 1 - s) : s;
        int id = ids[ids_base + l];
        int jj = (j < T_) ? j : 0;
        float v = tokt[id * T_ + jj];
        pre[i] = (j < T_) ? v : 0.f;
    }
    if (tid < 100) hbuf[0][tid] = 0.f;
    __syncthreads();
    float c = 0.f;
    for (int s = 0; s < L_; ++s) {
        const int cb = (s >> 4) & 1, sl = s & 15, par = s & 1;
        const float* xrow = &xbuf[cb][sl][0];
        const float* hrow = &hbuf[par][0];
        f2 aA = f2{0.f, 0.f}, aB = f2{0.f, 0.f};
#pragma unroll
        for (int j = 0; j < 25; ++j) {
            float4 hv = *(const float4*)&hrow[4 * j];
            aA = fma2(whA[2 * j], f2{hv.x, hv.y}, aA);
            aA = fma2(whA[2 * j + 1], f2{hv.z, hv.w}, aA);
            aB = fma2(whB[2 * j], f2{hv.x, hv.y}, aB);
            aB = fma2(whB[2 * j + 1], f2{hv.z, hv.w}, aB);
        }
#pragma unroll
        for (int j = 0; j < 13; ++j) {
            float4 xv = *(const float4*)&xrow[4 * j];
            aA = fma2(wiA[2 * j], f2{xv.x, xv.y}, aA);
            aB = fma2(wiB[2 * j], f2{xv.x, xv.y}, aB);
            aA = fma2(wiA[2 * j + 1], f2{xv.z, xv.w}, aA);
            aB = fma2(wiB[2 * j + 1], f2{xv.z, xv.w}, aB);
        }
        float pA = biasA + aA.x + aA.y;
        float pB = biasB + aB.x + aB.y;
        float sA = sigm(pA);
        float inB = r ? pB : 2.f * pB;
        float sB = sigm(inB);
        float gB = r ? sB : 2.f * sB - 1.f;
        float t0 = r ? sA * c : sA * gB;
        float t1 = dpp_xor1(t0);
        float cn = t0 + t1; c = cn;
        float th = 2.f * sigm(2.f * cn) - 1.f;
        float hv_ = gB * th;
        if (wr) {
            hbuf[par ^ 1][k] = hv_;
            int l = dir ? (L_ - 1 - s) : s;
            out[((size_t)b * L_ + l) * 204 + (dir ? 104 : 0) + k] = hv_;
        }
        if (sl == 15) {
            int nc = (s >> 4) + 1;
            if (nc < 32) {
#pragma unroll
                for (int i = 0; i < 4; ++i) { int e = tid + i * 256; xbuf[nc & 1][e >> 6][e & 63] = pre[i]; }
                if (nc + 1 < 32) {
#pragma unroll
                    for (int i = 0; i < 4; ++i) {
                        int e = tid + i * 256; int sl2 = e >> 6, j = e & 63;
                        int s2 = (nc + 1) * 16 + sl2;
                        int l2 = dir ? (L_ - 1 - s2) : s2;
                        int id = ids[ids_base + l2];
                        int jj = (j < T_) ? j : 0;
                        float v = tokt[id * T_ + jj];
                        pre[i] = (j < T_) ? v : 0.f;
                    }
                }
            }
        }
        __syncthreads();
    }
}

// ---------------- Attention: W_proj columns register-resident, padded LDS ----------------
__global__ __launch_bounds__(256, 1) void attn2(
    const float* __restrict__ lex, const int* __restrict__ pids,
    const int* __restrict__ bmes, const int* __restrict__ lmask,
    const float* __restrict__ pint, const float* __restrict__ wp,
    const float* __restrict__ bp, float* __restrict__ out)
{
    __shared__ __align__(16) float hid[32 * 100];
    __shared__ __align__(16) float catl[32 * 424];   // [32][4][106] padded
    __shared__ __align__(16) float vv[32 * 110];     // padded: 2-way max
    __shared__ float wts[128];

    const int b = blockIdx.x >> 4, ch = blockIdx.x & 15, l0 = ch * 32;
    const int tid = threadIdx.x;
    const size_t bl0 = (size_t)b * L_ + l0;

    // W_proj columns (f0, f1) into registers; coalesced across lanes per h.
    const int fi = tid & 63, wave = tid >> 6;
    const int f0 = fi, f1 = 64 + fi;
    f2 w0[50], w1[50];
#pragma unroll
    for (int j = 0; j < 50; ++j)
        w0[j] = f2{ wp[(2 * j) * 104 + f0], wp[(2 * j + 1) * 104 + f0] };
    if (f1 < 104) {
#pragma unroll
        for (int j = 0; j < 50; ++j)
            w1[j] = f2{ wp[(2 * j) * 104 + f1], wp[(2 * j + 1) * 104 + f1] };
    } else if (f1 == 104) {   // bias row -> s0
#pragma unroll
        for (int j = 0; j < 50; ++j) w1[j] = f2{ bp[2 * j], bp[2 * j + 1] };
    } else {
#pragma unroll
        for (int j = 0; j < 50; ++j) w1[j] = f2{0.f, 0.f};
    }

    // hidden = h_f + h_b; finalize out[...,0:100]
    for (int e = tid; e < 3200; e += 256) {
        int p = e / 100, q = e % 100; size_t bl = bl0 + p;
        float sv = out[bl * 204 + q] + out[bl * 204 + 104 + q];
        hid[p * 100 + q] = sv; out[bl * 204 + q] = sv;
    }
    // cat = [onehot(bmes,4) | lex(50) | pinyin(50)], padded stride
    for (int e = tid; e < 13312; e += 256) {
        int p = e / 416, rem = e % 416, w = rem / 104, f = rem % 104;
        size_t blw = (bl0 + p) * 4 + w; float v;
        if (f < 4)       v = (bmes[blw] == f) ? 1.f : 0.f;
        else if (f < 54) v = lex[blw * 50 + (f - 4)];
        else             v = pint[(size_t)pids[blw] * 50 + (f - 54)];
        catl[p * 424 + w * 106 + f] = v;
    }
    __syncthreads();

    // v[p][f] = W_col_f . hid[p]   (hid reads are wave-uniform broadcasts)
    for (int pp = 0; pp < 8; ++pp) {
        int p = wave * 8 + pp;
        const float4* h4 = (const float4*)&hid[p * 100];
        f2 a0{0.f,0.f}, a1{0.f,0.f}, a2{0.f,0.f}, a3{0.f,0.f};
#pragma unroll
        for (int j = 0; j < 25; ++j) {
            float4 hv = h4[j];
            a0 = fma2(w0[2 * j],     f2{hv.x, hv.y}, a0);
            a1 = fma2(w0[2 * j + 1], f2{hv.z, hv.w}, a1);
            a2 = fma2(w1[2 * j],     f2{hv.x, hv.y}, a2);
            a3 = fma2(w1[2 * j + 1], f2{hv.z, hv.w}, a3);
        }
        vv[p * 110 + f0] = a0.x + a0.y + a1.x + a1.y;
        if (f1 <= 104) vv[p * 110 + f1] = a2.x + a2.y + a3.x + a3.y;
    }
    __syncthreads();

    // scores + masked softmax over W=4
    if (tid < 128) {
        int p = tid >> 2, w = tid & 3;
        const f2* cr = (const f2*)&catl[p * 424 + w * 106];
        const f2* vr = (const f2*)&vv[p * 110];
        f2 a{0.f, 0.f};
#pragma unroll
        for (int ff = 0; ff < 52; ++ff) a = fma2(cr[ff], vr[ff], a);
        float sc = a.x + a.y + vv[p * 110 + 104];
        if (lmask[(bl0 + p) * 4 + w] == 0) sc = -1e9f;
        float mx = fmaxf(sc, __shfl_xor(sc, 1, 64)); mx = fmaxf(mx, __shfl_xor(mx, 2, 64));
        float e = __expf(sc - mx);
        float ssum = e + __shfl_xor(e, 1, 64); ssum += __shfl_xor(ssum, 2, 64);
        wts[tid] = e * __builtin_amdgcn_rcpf(ssum);
    }
    __syncthreads();

    // att -> out[...,100:204]
    for (int e = tid; e < 3328; e += 256) {
        int p = e / 104, f = e % 104;
        const float* cp = &catl[p * 424 + f];
        float a = wts[p * 4] * cp[0] + wts[p * 4 + 1] * cp[106]
                + wts[p * 4 + 2] * cp[212] + wts[p * 4 + 3] * cp[318];
        out[(bl0 + p) * 204 + 100 + f] = a;
    }
}

extern "C" void kernel_launch(void* const* d_in, const int* in_sizes, int n_in,
                              void* d_out, int out_size, void* d_ws, size_t ws_size,
                              hipStream_t stream) {
    const int*   ids   = (const int*)d_in[0];
    const float* lex   = (const float*)d_in[1];
    const int*   pids  = (const int*)d_in[2];
    const int*   bmes  = (const int*)d_in[3];
    const int*   lmask = (const int*)d_in[4];
    const float* tokt  = (const float*)d_in[6];
    const float* pint  = (const float*)d_in[7];
    const float* wihf  = (const float*)d_in[8];
    const float* whhf  = (const float*)d_in[9];
    const float* bihf  = (const float*)d_in[10];
    const float* bhhf  = (const float*)d_in[11];
    const float* wihb  = (const float*)d_in[12];
    const float* whhb  = (const float*)d_in[13];
    const float* bihb  = (const float*)d_in[14];
    const float* bhhb  = (const float*)d_in[15];
    const float* wp    = (const float*)d_in[16];
    const float* bp    = (const float*)d_in[17];
    float* out = (float*)d_out;

    const size_t need = (size_t)2 * XGN * sizeof(float);   // 104,857,600 B
    if (ws_size >= need) {
        float* xg = (float*)d_ws;
        xg_gemm<<<2048, 256, 0, stream>>>(ids, tokt, wihf, wihb, xg);
        lstm2<<<128, 256, 0, stream>>>(xg, whhf, bihf, bhhf, whhb, bihb, bhhb, out);
    } else {
        lstm_fb<<<128, 256, 0, stream>>>(ids, tokt, wihf, whhf, bihf, bhhf,
                                         wihb, whhb, bihb, bhhb, out);
    }
    attn2<<<1024, 256, 0, stream>>>(lex, pids, bmes, lmask, pint, wp, bp, out);
}

// Round 3
// 370.003 us; speedup vs baseline: 2.8941x; 1.6779x over previous
//
#include <hip/hip_runtime.h>

typedef float f2 __attribute__((ext_vector_type(2)));

__device__ __forceinline__ f2 fma2(f2 a, f2 b, f2 c) { return __builtin_elementwise_fma(a, b, c); }
__device__ __forceinline__ float sigm(float x) { float e = __expf(-x); return __builtin_amdgcn_rcpf(1.f + e); }

// quad_perm DPP: ctrl must be a literal
#define DPPQ(x, ctrl) __int_as_float(__builtin_amdgcn_mov_dpp(__float_as_int(x), (ctrl), 0xF, 0xF, true))
#define DPP_XOR1 0xB1  /* [1,0,3,2] */
#define DPP_XOR2 0x4E  /* [2,3,0,1] */

#define B_ 64
#define L_ 512
#define T_ 50
#define H_ 100
#define XGN (B_ * L_ * 400)   // floats per direction of xg scratch

// ---------------- xg GEMM: gate pre-activations from inputs, all steps ----------------
__global__ __launch_bounds__(256, 2) void xg_gemm(
    const int* __restrict__ ids, const float* __restrict__ tokt,
    const float* __restrict__ wihf, const float* __restrict__ wihb,
    float* __restrict__ xg)
{
    const int blk = blockIdx.x, dir = blk >> 10, rest = blk & 1023;
    const int b = rest >> 4, lc = rest & 15, l0 = lc * 32;
    const int tid = threadIdx.x, k_raw = tid >> 1, r = tid & 1;
    const int k = (k_raw < 100) ? k_raw : 99;
    const bool act = tid < 200;
    const int rowA = r * 100 + k, rowB = 200 + r * 100 + k;
    const float* wih = dir ? wihb : wihf;

    f2 wA2[25], wB2[25];
#pragma unroll
    for (int j = 0; j < 25; ++j) {
        wA2[j] = *(const f2*)&wih[rowA * T_ + 2 * j];   // rowA*200B: 8B-aligned
        wB2[j] = *(const f2*)&wih[rowB * T_ + 2 * j];
    }
#pragma unroll
    for (int j = 0; j < 25; ++j) { asm volatile("" : "+v"(wA2[j])); asm volatile("" : "+v"(wB2[j])); }

    float* xgd = xg + (size_t)dir * XGN;
    for (int p = 0; p < 32; ++p) {
        int l = l0 + p;
        int id = ids[b * L_ + l];                    // uniform -> s_load
        const float* xr = tokt + (size_t)id * T_;    // uniform row
        f2 aA{0.f, 0.f}, aB{0.f, 0.f};
#pragma unroll
        for (int j = 0; j < 25; ++j) {
            f2 xv = f2{xr[2 * j], xr[2 * j + 1]};    // uniform scalar loads
            aA = fma2(wA2[j], xv, aA);
            aB = fma2(wB2[j], xv, aB);
        }
        int idx = dir ? (L_ - 1 - l) : l;            // step-ordered store
        float* o = xgd + ((size_t)b * L_ + idx) * 400;
        if (act) { o[rowA] = aA.x + aA.y; o[rowB] = aB.x + aB.y; }
    }
}

// ---------------- BiLSTM recurrence v3: quad-of-lanes per hidden unit ----------------
// 512 threads. Quad kq owns unit k; lane rq holds ALL 4 gate rows restricted to
// h-segment [25*rq, 25*rq+25). Partial dots combined by 2-stage DPP transpose-reduce
// so lane rq ends owning gate rq (i,f,g,o). 100 weight floats/lane, asm-pinned.
__global__ __launch_bounds__(512, 1) void lstm3(
    const float* __restrict__ xg,
    const float* __restrict__ whhf, const float* __restrict__ bihf, const float* __restrict__ bhhf,
    const float* __restrict__ whhb, const float* __restrict__ bihb, const float* __restrict__ bhhb,
    float* __restrict__ out)
{
    __shared__ __align__(16) float xgbuf[2][6400];   // 16 steps x 400 gates, dbuf
    __shared__ __align__(16) float hbuf[2][116];     // 4 segs x 28 (pad 25..27 = 0)

    const int blk = blockIdx.x, b = blk >> 1, dir = blk & 1, tid = threadIdx.x;
    const float* whh = dir ? whhb : whhf;
    const float* bih = dir ? bihb : bihf;
    const float* bhh = dir ? bhhb : bhhf;
    const float* xgd = xg + (size_t)dir * XGN + (size_t)b * (L_ * 400);

    const int kq = tid >> 2, rq = tid & 3;
    const int k = (kq < 100) ? kq : 99;              // clamp idle quads
    const bool act = (kq < 100);
    const int row_g = rq * 100 + k;                  // gate row owned after transpose
    const int hoff = (k / 25) * 28 + (k % 25);       // padded h slot for unit k
    const int seg = rq * 25;

    // weights: w[r][j] = f2{W_hh[r*100+k][seg+2j], [seg+2j+1]}, tail y = 0
    f2 w[4][13];
#pragma unroll
    for (int r = 0; r < 4; ++r) {
        const float* wr = whh + (size_t)(r * 100 + k) * 100 + seg;
#pragma unroll
        for (int j = 0; j < 12; ++j) w[r][j] = f2{wr[2 * j], wr[2 * j + 1]};
        w[r][12] = f2{wr[24], 0.f};
    }
#pragma unroll
    for (int r = 0; r < 4; ++r)
#pragma unroll
        for (int j = 0; j < 13; ++j)
            asm volatile("" : "+v"(w[r][j]));        // pin: forbid re-load demotion

    const float bias = bih[row_g] + bhh[row_g];
    const float ascale = (rq == 2) ? 2.f : 1.f;      // tanh via 2*sigm(2x)-1 for gate g

    // stage chunk 0
    {
        const float4* s4 = (const float4*)xgd;
        float4* d4 = (float4*)xgbuf[0];
#pragma unroll
        for (int t = 0; t < 4; ++t) { int e = tid + 512 * t; if (e < 1600) d4[e] = s4[e]; }
    }
    if (tid < 232) ((float*)hbuf)[tid] = 0.f;        // zero h0 AND pads (stay 0 forever)
    __syncthreads();

    float c = 0.f;
    float4 pre[4];
    for (int s = 0; s < L_; ++s) {
        const int m = s >> 4, sl = s & 15, par = s & 1;
        if (sl == 0 && m + 1 < 32) {                 // T14: issue loads early...
            const float4* s4 = (const float4*)(xgd + (size_t)(m + 1) * 6400);
#pragma unroll
            for (int t = 0; t < 4; ++t) { int e = tid + 512 * t; pre[t] = (e < 1600) ? s4[e] : float4{0, 0, 0, 0}; }
        }
        if (sl == 8 && m + 1 < 32) {                 // ...write LDS late
            float4* d4 = (float4*)xgbuf[(m + 1) & 1];
#pragma unroll
            for (int t = 0; t < 4; ++t) { int e = tid + 512 * t; if (e < 1600) d4[e] = pre[t]; }
        }

        const float* hb = &hbuf[par][rq * 28];
        float4 h0 = ((const float4*)hb)[0], h1 = ((const float4*)hb)[1], h2 = ((const float4*)hb)[2];
        float4 h3 = ((const float4*)hb)[3], h4 = ((const float4*)hb)[4], h5 = ((const float4*)hb)[5];
        f2 ht = *(const f2*)(hb + 24);               // (h[seg+24], pad=0)

        f2 a0{0.f,0.f}, a1{0.f,0.f}, a2{0.f,0.f}, a3{0.f,0.f};
#define ROWDOT(A, R) \
        A = fma2(w[R][0],  f2{h0.x, h0.y}, A); A = fma2(w[R][1],  f2{h0.z, h0.w}, A); \
        A = fma2(w[R][2],  f2{h1.x, h1.y}, A); A = fma2(w[R][3],  f2{h1.z, h1.w}, A); \
        A = fma2(w[R][4],  f2{h2.x, h2.y}, A); A = fma2(w[R][5],  f2{h2.z, h2.w}, A); \
        A = fma2(w[R][6],  f2{h3.x, h3.y}, A); A = fma2(w[R][7],  f2{h3.z, h3.w}, A); \
        A = fma2(w[R][8],  f2{h4.x, h4.y}, A); A = fma2(w[R][9],  f2{h4.z, h4.w}, A); \
        A = fma2(w[R][10], f2{h5.x, h5.y}, A); A = fma2(w[R][11], f2{h5.z, h5.w}, A); \
        A = fma2(w[R][12], ht, A);
        ROWDOT(a0, 0) ROWDOT(a1, 1) ROWDOT(a2, 2) ROWDOT(a3, 3)
#undef ROWDOT
        float p0 = a0.x + a0.y, p1 = a1.x + a1.y, p2 = a2.x + a2.y, p3 = a3.x + a3.y;

        // transpose-reduce: lane rq <- sum over quad of p_rq
        // stage A (xor2): row r summed over {l, l^2}
        float q0 = p0 + DPPQ(p0, DPP_XOR2);
        float q1 = p1 + DPPQ(p1, DPP_XOR2);
        float q2 = p2 + DPPQ(p2, DPP_XOR2);
        float q3 = p3 + DPPQ(p3, DPP_XOR2);
        float sA = (rq & 2) ? q2 : q0;
        float sB = (rq & 2) ? q3 : q1;
        // stage B (xor1): complete the sum; lane rq gets row rq
        float fA = DPPQ(sA, DPP_XOR1), fB = DPPQ(sB, DPP_XOR1);
        float tot = (rq & 1) ? (sB + fB) : (sA + fA);

        float prea = tot + xgbuf[m & 1][sl * 400 + row_g] + bias;
        float aa = sigm(ascale * prea);
        float a = (rq == 2) ? (2.f * aa - 1.f) : aa;   // lane0:σ(i) 1:σ(f) 2:tanh(g) 3:σ(o)

        float bsw = DPPQ(a, DPP_XOR2);                 // 0:tanh(g) 1:σ(o) 2:σ(i) 3:σ(f)
        float t = (rq == 1) ? (a * c) : (a * bsw);     // lane0: i*g ; lane1: f*c
        float u = DPPQ(t, DPP_XOR1);
        float cn = t + u;                              // lanes 0,1: i*g + f*c
        c = cn;
        float th = 2.f * sigm(2.f * cn) - 1.f;         // tanh(c)
        float hv = bsw * th;                           // lane1: o * tanh(c)

        if (act && rq == 1) {
            hbuf[par ^ 1][hoff] = hv;
            int l = dir ? (L_ - 1 - s) : s;
            out[((size_t)b * L_ + l) * 204 + (dir ? 104 : 0) + k] = hv;
        }
        __syncthreads();
    }
}

// ---------------- Fallback BiLSTM (used when ws too small) ----------------
__global__ __launch_bounds__(256, 1) void lstm_fb(
    const int* __restrict__ ids, const float* __restrict__ tokt,
    const float* __restrict__ wihf, const float* __restrict__ whhf,
    const float* __restrict__ bihf, const float* __restrict__ bhhf,
    const float* __restrict__ wihb, const float* __restrict__ whhb,
    const float* __restrict__ bihb, const float* __restrict__ bhhb,
    float* __restrict__ out)
{
    __shared__ __align__(16) float xbuf[2][16][64];
    __shared__ __align__(16) float hbuf[2][100];
    const int blk = blockIdx.x;
    const int b = blk >> 1, dir = blk & 1;
    const int tid = threadIdx.x;
    const float* wih = dir ? wihb : wihf;
    const float* whh = dir ? whhb : whhf;
    const float* bih = dir ? bihb : bihf;
    const float* bhh = dir ? bhhb : bhhf;
    const int k_raw = tid >> 1, r = tid & 1;
    const int k = (k_raw < 100) ? k_raw : 99;
    const bool wr = (tid < 200) && (r == 1);
    const int rowA = (r ? 100 : 0) + k;
    const int rowB = (r ? 300 : 200) + k;
    f2 wiA[26], wiB[26], whA[50], whB[50];
#pragma unroll
    for (int j = 0; j < 25; ++j) {
        wiA[j] = *(const f2*)&wih[rowA * T_ + 2 * j];
        wiB[j] = *(const f2*)&wih[rowB * T_ + 2 * j];
    }
    wiA[25] = f2{0.f, 0.f}; wiB[25] = f2{0.f, 0.f};
#pragma unroll
    for (int j = 0; j < 50; ++j) {
        whA[j] = *(const f2*)&whh[rowA * H_ + 2 * j];
        whB[j] = *(const f2*)&whh[rowB * H_ + 2 * j];
    }
    const float biasA = bih[rowA] + bhh[rowA];
    const float biasB = bih[rowB] + bhh[rowB];
    const int ids_base = b * L_;
    float pre[4];
#pragma unroll
    for (int i = 0; i < 4; ++i) {
        int e = tid + i * 256; int sl = e >> 6, j = e & 63;
        int l = dir ? (L_ - 1 - sl) : sl;
        int id = ids[ids_base + l];
        int jj = (j < T_) ? j : 0;
        float v = tokt[id * T_ + jj];
        pre[i] = (j < T_) ? v : 0.f;
    }
#pragma unroll
    for (int i = 0; i < 4; ++i) { int e = tid + i * 256; xbuf[0][e >> 6][e & 63] = pre[i]; }
#pragma unroll
    for (int i = 0; i < 4; ++i) {
        int e = tid + i * 256; int sl = e >> 6, j = e & 63;
        int s = 16 + sl;
        int l = dir ? (L_ - 1 - s) : s;
        int id = ids[ids_base + l];
        int jj = (j < T_) ? j : 0;
        float v = tokt[id * T_ + jj];
        pre[i] = (j < T_) ? v : 0.f;
    }
    if (tid < 100) hbuf[0][tid] = 0.f;
    __syncthreads();
    float c = 0.f;
    for (int s = 0; s < L_; ++s) {
        const int cb = (s >> 4) & 1, sl = s & 15, par = s & 1;
        const float* xrow = &xbuf[cb][sl][0];
        const float* hrow = &hbuf[par][0];
        f2 aA = f2{0.f, 0.f}, aB = f2{0.f, 0.f};
#pragma unroll
        for (int j = 0; j < 25; ++j) {
            float4 hv = *(const float4*)&hrow[4 * j];
            aA = fma2(whA[2 * j], f2{hv.x, hv.y}, aA);
            aA = fma2(whA[2 * j + 1], f2{hv.z, hv.w}, aA);
            aB = fma2(whB[2 * j], f2{hv.x, hv.y}, aB);
            aB = fma2(whB[2 * j + 1], f2{hv.z, hv.w}, aB);
        }
#pragma unroll
        for (int j = 0; j < 13; ++j) {
            float4 xv = *(const float4*)&xrow[4 * j];
            aA = fma2(wiA[2 * j], f2{xv.x, xv.y}, aA);
            aB = fma2(wiB[2 * j], f2{xv.x, xv.y}, aB);
            aA = fma2(wiA[2 * j + 1], f2{xv.z, xv.w}, aA);
            aB = fma2(wiB[2 * j + 1], f2{xv.z, xv.w}, aB);
        }
        float pA = biasA + aA.x + aA.y;
        float pB = biasB + aB.x + aB.y;
        float sA = sigm(pA);
        float inB = r ? pB : 2.f * pB;
        float sB = sigm(inB);
        float gB = r ? sB : 2.f * sB - 1.f;
        float t0 = r ? sA * c : sA * gB;
        float t1 = DPPQ(t0, DPP_XOR1);
        float cn = t0 + t1; c = cn;
        float th = 2.f * sigm(2.f * cn) - 1.f;
        float hv_ = gB * th;
        if (wr) {
            hbuf[par ^ 1][k] = hv_;
            int l = dir ? (L_ - 1 - s) : s;
            out[((size_t)b * L_ + l) * 204 + (dir ? 104 : 0) + k] = hv_;
        }
        if (sl == 15) {
            int nc = (s >> 4) + 1;
            if (nc < 32) {
#pragma unroll
                for (int i = 0; i < 4; ++i) { int e = tid + i * 256; xbuf[nc & 1][e >> 6][e & 63] = pre[i]; }
                if (nc + 1 < 32) {
#pragma unroll
                    for (int i = 0; i < 4; ++i) {
                        int e = tid + i * 256; int sl2 = e >> 6, j = e & 63;
                        int s2 = (nc + 1) * 16 + sl2;
                        int l2 = dir ? (L_ - 1 - s2) : s2;
                        int id = ids[ids_base + l2];
                        int jj = (j < T_) ? j : 0;
                        float v = tokt[id * T_ + jj];
                        pre[i] = (j < T_) ? v : 0.f;
                    }
                }
            }
        }
        __syncthreads();
    }
}

// ---------------- Attention v3: 16-l blocks, >=2 resident/CU, row-copy gathers ----------------
__global__ __launch_bounds__(256, 2) void attn3(
    const float* __restrict__ lex, const int* __restrict__ pids,
    const int* __restrict__ bmes, const int* __restrict__ lmask,
    const float* __restrict__ pint, const float* __restrict__ wp,
    const float* __restrict__ bp, float* __restrict__ out)
{
    __shared__ __align__(16) float hid[16 * 100];     // 6.4 KB
    __shared__ __align__(16) float catl[16 * 426];    // 27.3 KB, p-stride 426 (bank spread)
    __shared__ __align__(16) float vv[16 * 110];      // 7.0 KB
    __shared__ float wts[64];

    const int b = blockIdx.x >> 5, ch = blockIdx.x & 31, l0 = ch * 16;
    const int tid = threadIdx.x;
    const size_t bl0 = (size_t)b * L_ + l0;

    // W_proj column fcol (105 = bias row) register-resident, pinned
    const int fcol = tid & 127, ph = tid >> 7;
    f2 wc[50];
    if (fcol < 104) {
#pragma unroll
        for (int j = 0; j < 50; ++j)
            wc[j] = f2{wp[(2 * j) * 104 + fcol], wp[(2 * j + 1) * 104 + fcol]};
    } else if (fcol == 104) {
#pragma unroll
        for (int j = 0; j < 50; ++j) wc[j] = f2{bp[2 * j], bp[2 * j + 1]};
    } else {
#pragma unroll
        for (int j = 0; j < 50; ++j) wc[j] = f2{0.f, 0.f};
    }
#pragma unroll
    for (int j = 0; j < 50; ++j) asm volatile("" : "+v"(wc[j]));

    // hidden = h_f + h_b; finalize out[...,0:100]
    for (int e = tid; e < 1600; e += 256) {
        int p = e / 100, q = e % 100; size_t bl = bl0 + p;
        float sv = out[bl * 204 + q] + out[bl * 204 + 104 + q];
        hid[p * 100 + q] = sv; out[bl * 204 + q] = sv;
    }
    // bmes one-hot
    if (tid < 64) {
        int p = tid >> 2, w = tid & 3;
        int bm = bmes[(bl0 + p) * 4 + w];
        float* cb = &catl[p * 426 + w * 106];
        cb[0] = (bm == 0) ? 1.f : 0.f; cb[1] = (bm == 1) ? 1.f : 0.f;
        cb[2] = (bm == 2) ? 1.f : 0.f; cb[3] = (bm == 3) ? 1.f : 0.f;
    }
    // lexicon 50-float rows: fully coalesced
    for (int e = tid; e < 3200; e += 256) {
        int pr = e / 50, f = e % 50;
        int p = pr >> 2, w = pr & 3;
        catl[p * 426 + w * 106 + 4 + f] = lex[((bl0 + p) * 4 + w) * 50 + f];
    }
    // pinyin rows: quad-per-row copy (row-contiguous gather)
    {
        int pr = tid >> 2, q4 = tid & 3;
        int p = pr >> 2, w = pr & 3;
        int pid = pids[(bl0 + p) * 4 + w];
        const float* src = pint + (size_t)pid * 50;
        float* dst = &catl[p * 426 + w * 106 + 54];
        int j0 = q4 * 13, n = (q4 == 3) ? 11 : 13;
        for (int j = 0; j < n; ++j) dst[j0 + j] = src[j0 + j];
    }
    __syncthreads();

    // v[p][fcol] = col_fcol(W_proj) . hid[p]  (hid reads broadcast)
    if (fcol < 105) {
#pragma unroll
        for (int pp = 0; pp < 8; ++pp) {
            int p = ph * 8 + pp;
            const float4* h4 = (const float4*)&hid[p * 100];
            f2 a{0.f, 0.f};
#pragma unroll
            for (int j = 0; j < 25; ++j) {
                float4 hv = h4[j];
                a = fma2(wc[2 * j],     f2{hv.x, hv.y}, a);
                a = fma2(wc[2 * j + 1], f2{hv.z, hv.w}, a);
            }
            vv[p * 110 + fcol] = a.x + a.y;
        }
    }
    __syncthreads();

    // scores + masked softmax over W=4
    if (tid < 64) {
        int p = tid >> 2, w = tid & 3;
        const f2* cr = (const f2*)&catl[p * 426 + w * 106];
        const f2* vr = (const f2*)&vv[p * 110];
        f2 a{0.f, 0.f};
#pragma unroll
        for (int ff = 0; ff < 52; ++ff) a = fma2(cr[ff], vr[ff], a);
        float sc = a.x + a.y + vv[p * 110 + 104];
        if (lmask[(bl0 + p) * 4 + w] == 0) sc = -1e9f;
        float mx = fmaxf(sc, __shfl_xor(sc, 1, 64)); mx = fmaxf(mx, __shfl_xor(mx, 2, 64));
        float e = __expf(sc - mx);
        float ss = e + __shfl_xor(e, 1, 64); ss += __shfl_xor(ss, 2, 64);
        wts[tid] = e * __builtin_amdgcn_rcpf(ss);
    }
    __syncthreads();

    // att -> out[...,100:204]
    for (int e = tid; e < 1664; e += 256) {
        int p = e / 104, f = e % 104;
        const float* cp = &catl[p * 426 + f];
        float a = wts[p * 4] * cp[0] + wts[p * 4 + 1] * cp[106]
                + wts[p * 4 + 2] * cp[212] + wts[p * 4 + 3] * cp[318];
        out[(bl0 + p) * 204 + 100 + f] = a;
    }
}

extern "C" void kernel_launch(void* const* d_in, const int* in_sizes, int n_in,
                              void* d_out, int out_size, void* d_ws, size_t ws_size,
                              hipStream_t stream) {
    const int*   ids   = (const int*)d_in[0];
    const float* lex   = (const float*)d_in[1];
    const int*   pids  = (const int*)d_in[2];
    const int*   bmes  = (const int*)d_in[3];
    const int*   lmask = (const int*)d_in[4];
    const float* tokt  = (const float*)d_in[6];
    const float* pint  = (const float*)d_in[7];
    const float* wihf  = (const float*)d_in[8];
    const float* whhf  = (const float*)d_in[9];
    const float* bihf  = (const float*)d_in[10];
    const float* bhhf  = (const float*)d_in[11];
    const float* wihb  = (const float*)d_in[12];
    const float* whhb  = (const float*)d_in[13];
    const float* bihb  = (const float*)d_in[14];
    const float* bhhb  = (const float*)d_in[15];
    const float* wp    = (const float*)d_in[16];
    const float* bp    = (const float*)d_in[17];
    float* out = (float*)d_out;

    const size_t need = (size_t)2 * XGN * sizeof(float);   // 104,857,600 B
    if (ws_size >= need) {
        float* xg = (float*)d_ws;
        xg_gemm<<<2048, 256, 0, stream>>>(ids, tokt, wihf, wihb, xg);
        lstm3<<<128, 512, 0, stream>>>(xg, whhf, bihf, bhhf, whhb, bihb, bhhb, out);
    } else {
        lstm_fb<<<128, 256, 0, stream>>>(ids, tokt, wihf, whhf, bihf, bhhf,
                                         wihb, whhb, bihb, bhhb, out);
    }
    attn3<<<2048, 256, 0, stream>>>(lex, pids, bmes, lmask, pint, wp, bp, out);
}